// Round 1
// baseline (433.876 us; speedup 1.0000x reference)
//
#include <hip/hip_runtime.h>

// Problem: x [B=256,1,512,512] f32; weights [512,4,1]; biases [512,1].
// out[b,i] = relu( dot(ring_means(b,i,0..3), weights[i,:,0]) + biases[i] )
// ring index per corner for pixel (r,c):
//   tl: max(r,c)  tr: max(r,511-c)  bl: max(511-r,c)  br: max(511-r,511-c)
// Strategy: one streaming pass over x accumulating ring SUMS into
// ws[b][ring][corner]; tiny second kernel does mean+linear+bias+relu.

#define HH 512
#define WW 512
#define NRING 512

// ---------------- Kernel 1: ring sums ----------------
// grid: B*8 blocks of 256 threads (4 waves). Block = image b, row chunk of 64.
// Wave w handles rows chunk*64 + w*16 + k (k=0..15), one full row per iter:
// lane loads float4 at c=4*lane (group A) and c=256+4*lane (group B).
// Per row, per corner the ring is either uniform (=r or 511-r) -> masked row
// sum, wave-reduced, one LDS atomic per row; or varies as c / 511-c ->
// per-lane REGISTER bins (32 regs), flushed once at the end.
__global__ __launch_bounds__(256, 4)
void ring_sum_kernel(const float* __restrict__ x, float* __restrict__ rs) {
    __shared__ float bins[4 * NRING];   // [corner][ring], 8 KiB
    const int tid  = threadIdx.x;
    const int lane = tid & 63;
    const int wave = tid >> 6;
    const int b     = blockIdx.x >> 3;
    const int chunk = blockIdx.x & 7;

    for (int t = tid; t < 4 * NRING; t += 256) bins[t] = 0.f;
    __syncthreads();

    float vTL[8] = {0,0,0,0,0,0,0,0};
    float vTR[8] = {0,0,0,0,0,0,0,0};
    float vBL[8] = {0,0,0,0,0,0,0,0};
    float vBR[8] = {0,0,0,0,0,0,0,0};

    const float4* img = (const float4*)x + (size_t)b * (HH * WW / 4);
    const int cA = 4 * lane;        // columns cA..cA+3
    const int cB = 256 + 4 * lane;  // columns cB..cB+3

    for (int k = 0; k < 16; ++k) {
        const int r = chunk * 64 + wave * 16 + k;
        const int s = 511 - r;
        const float4* rowp = img + r * (WW / 4);
        float4 a  = rowp[lane];
        float4 bb = rowp[64 + lane];
        float uTL = 0.f, uTR = 0.f, uBL = 0.f, uBR = 0.f;

        if (r < 256) {
            // group A (c<256): bl uniform, tr varying; tl,br mixed
            #pragma unroll
            for (int j = 0; j < 4; ++j) {
                float v = (&a.x)[j]; int c = cA + j;
                uBL += v;
                vTR[j] += v;
                float sel  = (c <= r) ? v : 0.f; uTL += sel;  vTL[j] += v - sel;
                float sel2 = (c >= r) ? v : 0.f; uBR += sel2; vBR[j] += v - sel2;
            }
            // group B (c>=256): br uniform, tl varying; tr,bl mixed
            #pragma unroll
            for (int j = 0; j < 4; ++j) {
                float v = (&bb.x)[j]; int c = cB + j;
                uBR += v;
                vTL[4 + j] += v;
                float sel  = (c >= s) ? v : 0.f; uTR += sel;  vTR[4 + j] += v - sel;
                float sel2 = (c <= s) ? v : 0.f; uBL += sel2; vBL[4 + j] += v - sel2;
            }
        } else {
            // group A: tl uniform, br varying; tr,bl mixed
            #pragma unroll
            for (int j = 0; j < 4; ++j) {
                float v = (&a.x)[j]; int c = cA + j;
                uTL += v;
                vBR[j] += v;
                float sel  = (c >= s) ? v : 0.f; uTR += sel;  vTR[j] += v - sel;
                float sel2 = (c <= s) ? v : 0.f; uBL += sel2; vBL[j] += v - sel2;
            }
            // group B: tr uniform, bl varying; tl,br mixed
            #pragma unroll
            for (int j = 0; j < 4; ++j) {
                float v = (&bb.x)[j]; int c = cB + j;
                uTR += v;
                vBL[4 + j] += v;
                float sel  = (c <= r) ? v : 0.f; uTL += sel;  vTL[4 + j] += v - sel;
                float sel2 = (c >= r) ? v : 0.f; uBR += sel2; vBR[4 + j] += v - sel2;
            }
        }

        // wave-reduce the 4 uniform (row-constant-ring) sums
        for (int off = 32; off > 0; off >>= 1) {
            uTL += __shfl_down(uTL, off);
            uTR += __shfl_down(uTR, off);
            uBL += __shfl_down(uBL, off);
            uBR += __shfl_down(uBR, off);
        }
        if (lane == 0) {
            atomicAdd(&bins[0 * NRING + r], uTL);
            atomicAdd(&bins[1 * NRING + r], uTR);
            atomicAdd(&bins[2 * NRING + s], uBL);
            atomicAdd(&bins[3 * NRING + s], uBR);
        }
    }

    // flush per-lane register bins (ring depends only on owned column c)
    #pragma unroll
    for (int e = 0; e < 8; ++e) {
        int c = (e < 4) ? (cA + e) : (cB + e - 4);
        atomicAdd(&bins[0 * NRING + c],         vTL[e]);
        atomicAdd(&bins[1 * NRING + (511 - c)], vTR[e]);
        atomicAdd(&bins[2 * NRING + c],         vBL[e]);
        atomicAdd(&bins[3 * NRING + (511 - c)], vBR[e]);
    }
    __syncthreads();

    // block -> global: rs[b][ring][corner]
    float* out = rs + (size_t)b * (4 * NRING);
    for (int t = tid; t < 4 * NRING; t += 256) {
        int corner = t >> 9;
        int ring   = t & 511;
        atomicAdd(&out[ring * 4 + corner], bins[t]);
    }
}

// ---------------- Kernel 2: mean + linear + bias + relu ----------------
__global__ __launch_bounds__(256)
void linear_kernel(const float* __restrict__ rs, const float* __restrict__ wts,
                   const float* __restrict__ bias, float* __restrict__ out, int n) {
    int idx = blockIdx.x * 256 + threadIdx.x;
    if (idx >= n) return;
    int i = idx & 511;
    float4 sgm = ((const float4*)rs)[idx];        // [b][i][4] ring sums
    float4 w   = ((const float4*)wts)[i];         // weights[i][0..3][0]
    float inv  = 1.0f / (float)(2 * i + 1);
    float val  = (sgm.x * w.x + sgm.y * w.y + sgm.z * w.z + sgm.w * w.w) * inv
               + bias[i];
    out[idx] = fmaxf(val, 0.0f);
}

extern "C" void kernel_launch(void* const* d_in, const int* in_sizes, int n_in,
                              void* d_out, int out_size, void* d_ws, size_t ws_size,
                              hipStream_t stream) {
    const float* x    = (const float*)d_in[0];
    const float* wts  = (const float*)d_in[1];
    const float* bias = (const float*)d_in[2];
    float* out = (float*)d_out;

    const int B = in_sizes[0] / (HH * WW);   // 256
    float* rs = (float*)d_ws;                // [B][512][4] = 2 MiB

    hipMemsetAsync(rs, 0, (size_t)B * 4 * NRING * sizeof(float), stream);

    ring_sum_kernel<<<dim3(B * 8), dim3(256), 0, stream>>>(x, rs);

    const int n = B * NRING;                 // == out_size
    linear_kernel<<<dim3((n + 255) / 256), dim3(256), 0, stream>>>(rs, wts, bias, out, n);
}